// Round 1
// baseline (174.679 us; speedup 1.0000x reference)
//
#include <hip/hip_runtime.h>

#define BB 8
#define CC 384
#define HH 64
#define WW 64
#define NH 6
#define HD 64
#define PLANE (HH*WW)   /* 4096 */
#define QKSCALE 0.125f

__global__ __launch_bounds__(256) void dilate_attn_kernel(
    const float* __restrict__ qg, const float* __restrict__ kg,
    const float* __restrict__ vg, float* __restrict__ outg) {
  const int blk  = blockIdx.x;
  const int nyb  = HH / 4;
  const int y0   = (blk % nyb) * 4;
  const int bh   = blk / nyb;          // b*NH + head
  const int head = bh % NH;
  const int b    = bh / NH;
  const int lane = threadIdx.x & 63;
  const int warp = threadIdx.x >> 6;
  const int y = y0 + warp;
  const int x = lane;

  const long slab = ((long)(b * CC + head * HD)) * PLANE;
  const float* qs = qg + slab + y * WW + x;
  const float* ks = kg + slab;
  const float* vs = vg + slab;

  // 3x3 neighbor offsets (clamped) + validity masks
  int off[9]; float m[9];
#pragma unroll
  for (int di = 0; di < 3; ++di) {
#pragma unroll
    for (int dj = 0; dj < 3; ++dj) {
      const int yy = y + di - 1, xx = x + dj - 1;
      const bool valid = (yy >= 0) && (yy < HH) && (xx >= 0) && (xx < WW);
      const int yc = min(max(yy, 0), HH - 1);
      const int xc = min(max(xx, 0), WW - 1);
      off[di * 3 + dj] = yc * WW + xc;
      m[di * 3 + dj] = valid ? 1.0f : 0.0f;
    }
  }

  // QK^T: 9 scores, K = 64 channels, channel stride = PLANE
  float s[9];
#pragma unroll
  for (int i = 0; i < 9; ++i) s[i] = 0.0f;

#pragma unroll 4
  for (int d = 0; d < HD; ++d) {
    const float qv = qs[d * PLANE];
#pragma unroll
    for (int i = 0; i < 9; ++i)
      s[i] = fmaf(qv, ks[d * PLANE + off[i]], s[i]);
  }

  // mask (zero-padded k => score exactly 0, as in reference), scale, softmax over 9
  float mx = -1e30f;
#pragma unroll
  for (int i = 0; i < 9; ++i) { s[i] = s[i] * m[i] * QKSCALE; mx = fmaxf(mx, s[i]); }
  float sum = 0.0f;
#pragma unroll
  for (int i = 0; i < 9; ++i) { s[i] = __expf(s[i] - mx); sum += s[i]; }
  const float inv = 1.0f / sum;
#pragma unroll
  for (int i = 0; i < 9; ++i) s[i] = s[i] * inv * m[i];  // fold v-padding mask into p

  // PV: stream 4 channels at a time, write 16B-aligned float4 (64B per chunk pair)
  float* outp = outg + ((long)((b * HH + y) * WW + x)) * CC + head * HD;
#pragma unroll 2
  for (int d0 = 0; d0 < HD; d0 += 4) {
    float a0 = 0.f, a1 = 0.f, a2 = 0.f, a3 = 0.f;
#pragma unroll
    for (int i = 0; i < 9; ++i) {
      const float p = s[i];
      const float* vp = vs + d0 * PLANE + off[i];
      a0 = fmaf(p, vp[0 * PLANE], a0);
      a1 = fmaf(p, vp[1 * PLANE], a1);
      a2 = fmaf(p, vp[2 * PLANE], a2);
      a3 = fmaf(p, vp[3 * PLANE], a3);
    }
    float4 o; o.x = a0; o.y = a1; o.z = a2; o.w = a3;
    *reinterpret_cast<float4*>(outp + d0) = o;
  }
}

extern "C" void kernel_launch(void* const* d_in, const int* in_sizes, int n_in,
                              void* d_out, int out_size, void* d_ws, size_t ws_size,
                              hipStream_t stream) {
  const float* q = (const float*)d_in[0];
  const float* k = (const float*)d_in[1];
  const float* v = (const float*)d_in[2];
  float* out = (float*)d_out;
  const int blocks = BB * NH * (HH / 4);  // 768
  dilate_attn_kernel<<<blocks, 256, 0, stream>>>(q, k, v, out);
}

// Round 2
// 53.906 us; speedup vs baseline: 3.2404x; 3.2404x over previous
//
#include <hip/hip_runtime.h>

#define BB 8
#define CC 384
#define HH 64
#define WW 64
#define NH 6
#define HD 64
#define PLANE (HH*WW)   /* 4096 */
#define QKSCALE 0.125f
#define DCHUNK 16

__global__ __launch_bounds__(256, 3) void dilate_attn_kernel(
    const float* __restrict__ qg, const float* __restrict__ kg,
    const float* __restrict__ vg, float* __restrict__ outg) {
  const int blk  = blockIdx.x;
  const int nyb  = HH / 4;
  const int y0   = (blk % nyb) * 4;
  const int bh   = blk / nyb;          // b*NH + head
  const int head = bh % NH;
  const int b    = bh / NH;
  const int lane = threadIdx.x & 63;
  const int warp = threadIdx.x >> 6;
  const int y = y0 + warp;
  const int x = lane;

  const int laneL = (lane - 1) & 63;   // srcLane for value at x-1 (wraps, masked)
  const int laneR = (lane + 1) & 63;   // srcLane for value at x+1

  const long slab = ((long)(b * CC + head * HD)) * PLANE;
  const float* qs = qg + slab + y * WW + x;

  // 3 row bases (clamped) + validity masks m[r][dx]
  const float* krow[3];
  const float* vrow[3];
  float m[9];
#pragma unroll
  for (int r = 0; r < 3; ++r) {
    const int yy = y + r - 1;
    const int yc = min(max(yy, 0), HH - 1);
    krow[r] = kg + slab + yc * WW + x;
    vrow[r] = vg + slab + yc * WW + x;
    const bool rowok = (yy >= 0) && (yy < HH);
#pragma unroll
    for (int dx = 0; dx < 3; ++dx) {
      const int xx = x + dx - 1;
      m[r * 3 + dx] = (rowok && xx >= 0 && xx < WW) ? 1.0f : 0.0f;
    }
  }

  // ---- QK^T: t[r][dx](x) = sum_d k_r,d(x) * q_d(x - dx) ----
  float t[9];
#pragma unroll
  for (int i = 0; i < 9; ++i) t[i] = 0.0f;

  for (int d0 = 0; d0 < HD; d0 += DCHUNK) {
    float qv[DCHUNK], kv[3][DCHUNK];
#pragma unroll
    for (int dd = 0; dd < DCHUNK; ++dd) qv[dd] = qs[(d0 + dd) * PLANE];
#pragma unroll
    for (int r = 0; r < 3; ++r)
#pragma unroll
      for (int dd = 0; dd < DCHUNK; ++dd) kv[r][dd] = krow[r][(d0 + dd) * PLANE];

#pragma unroll
    for (int dd = 0; dd < DCHUNK; ++dd) {
      const float qc = qv[dd];
      const float qm = __shfl(qc, laneL);  // q(x-1)
      const float qp = __shfl(qc, laneR);  // q(x+1)
#pragma unroll
      for (int r = 0; r < 3; ++r) {
        const float kc = kv[r][dd];
        t[r * 3 + 0] = fmaf(kc, qp, t[r * 3 + 0]);  // dx=-1 uses q(x+1)
        t[r * 3 + 1] = fmaf(kc, qc, t[r * 3 + 1]);  // dx= 0
        t[r * 3 + 2] = fmaf(kc, qm, t[r * 3 + 2]);  // dx=+1 uses q(x-1)
      }
    }
  }

  // gather scores: s[r,dx](x) = t[r,dx](x+dx), mask, scale
  float s[9];
#pragma unroll
  for (int i = 0; i < 9; ++i) {
    const int dx = (i % 3) - 1;
    s[i] = __shfl(t[i], (lane + dx) & 63) * m[i] * QKSCALE;
  }

  // softmax over 9 (masked entries are exactly 0, matching zero-padded ref)
  float mx = s[0];
#pragma unroll
  for (int i = 1; i < 9; ++i) mx = fmaxf(mx, s[i]);
  float sum = 0.0f;
#pragma unroll
  for (int i = 0; i < 9; ++i) { s[i] = __expf(s[i] - mx); sum += s[i]; }
  const float inv = 1.0f / sum;
#pragma unroll
  for (int i = 0; i < 9; ++i) s[i] = s[i] * inv * m[i];  // fold v-pad mask into p

  // pre-shift p: P[r,dx](j) = p[r,dx](j - dx), zero the out-of-image edge lanes
  float P[9];
#pragma unroll
  for (int i = 0; i < 9; ++i) {
    const int dx = (i % 3) - 1;
    float pe = __shfl(s[i], (lane - dx) & 63);
    if (dx == 1 && lane == 0) pe = 0.0f;
    if (dx == -1 && lane == 63) pe = 0.0f;
    P[i] = pe;
  }

  // ---- PV: c_dx(j) = sum_r P[r,dx](j) * v_r(j);  out(x) = sum_dx c_dx(x+dx) ----
  float* outp = outg + ((long)((b * HH + y) * WW + x)) * CC + head * HD;

  for (int d0 = 0; d0 < HD; d0 += DCHUNK) {
    float vv[3][DCHUNK];
#pragma unroll
    for (int r = 0; r < 3; ++r)
#pragma unroll
      for (int dd = 0; dd < DCHUNK; ++dd) vv[r][dd] = vrow[r][(d0 + dd) * PLANE];

    float o[DCHUNK];
#pragma unroll
    for (int dd = 0; dd < DCHUNK; ++dd) {
      float cm = 0.f, c0 = 0.f, cp = 0.f;
#pragma unroll
      for (int r = 0; r < 3; ++r) {
        const float vc = vv[r][dd];
        cm = fmaf(P[r * 3 + 0], vc, cm);
        c0 = fmaf(P[r * 3 + 1], vc, c0);
        cp = fmaf(P[r * 3 + 2], vc, cp);
      }
      o[dd] = c0 + __shfl(cm, laneL) + __shfl(cp, laneR);
    }
#pragma unroll
    for (int dd = 0; dd < DCHUNK; dd += 4) {
      float4 ov; ov.x = o[dd]; ov.y = o[dd + 1]; ov.z = o[dd + 2]; ov.w = o[dd + 3];
      *reinterpret_cast<float4*>(outp + d0 + dd) = ov;
    }
  }
}

extern "C" void kernel_launch(void* const* d_in, const int* in_sizes, int n_in,
                              void* d_out, int out_size, void* d_ws, size_t ws_size,
                              hipStream_t stream) {
  const float* q = (const float*)d_in[0];
  const float* k = (const float*)d_in[1];
  const float* v = (const float*)d_in[2];
  float* out = (float*)d_out;
  const int blocks = BB * NH * (HH / 4);  // 768
  dilate_attn_kernel<<<blocks, 256, 0, stream>>>(q, k, v, out);
}